// Round 15
// baseline (307.998 us; speedup 1.0000x reference)
//
#include <hip/hip_runtime.h>

#define HH 4  // heads

typedef __attribute__((ext_vector_type(8))) short bf16x8;
typedef __attribute__((ext_vector_type(4))) float f32x4;

__device__ __forceinline__ float lrelu(float v) { return (v >= 0.0f) ? v : 0.2f * v; }

__device__ __forceinline__ unsigned short f2bf(float x) {
    union { float f; unsigned u; } v; v.f = x;
    unsigned r = (v.u + 0x7FFFu + ((v.u >> 16) & 1u)) >> 16;
    return (unsigned short)r;
}
__device__ __forceinline__ float bf2f(unsigned short b) {
    union { unsigned u; float f; } v; v.u = ((unsigned)b) << 16;
    return v.f;
}
__device__ __forceinline__ float bf2f_lo(unsigned u) {
    union { unsigned x; float f; } v; v.x = u << 16;
    return v.f;
}
__device__ __forceinline__ float bf2f_hi(unsigned u) {
    union { unsigned x; float f; } v; v.x = u & 0xffff0000u;
    return v.f;
}

// ============================ CSR build ============================
__global__ void hist_kernel(const int* __restrict__ dst, int* __restrict__ deg, int E) {
    int i = blockIdx.x * blockDim.x + threadIdx.x;
    if (i < E) atomicAdd(&deg[dst[i]], 1);
}

__global__ void scan_block(const int* __restrict__ deg, int* __restrict__ rs,
                           int* __restrict__ bsum, int n) {
    __shared__ int buf[1024];
    int i = blockIdx.x * 1024 + threadIdx.x;
    int v = (i < n) ? deg[i] : 0;
    buf[threadIdx.x] = v;
    __syncthreads();
    for (int off = 1; off < 1024; off <<= 1) {
        int t = (threadIdx.x >= off) ? buf[threadIdx.x - off] : 0;
        __syncthreads();
        buf[threadIdx.x] += t;
        __syncthreads();
    }
    if (i < n) rs[i + 1] = buf[threadIdx.x];
    if (threadIdx.x == 1023) bsum[blockIdx.x] = buf[1023];
}

// merged top-level scan: each thread serially prefixes bsum (<=30 entries, L2-hot)
__global__ void scan_add(int* __restrict__ rs, const int* __restrict__ bsum, int n) {
    int i = blockIdx.x * blockDim.x + threadIdx.x;
    if (i == 0) rs[0] = 0;
    if (i < n) {
        int blk = i >> 10;
        int pre = 0;
        for (int b = 0; b < blk; ++b) pre += bsum[b];
        rs[i + 1] += pre;
    }
}

__global__ void scatter_kernel(const int* __restrict__ src, const int* __restrict__ dst,
                               const int* __restrict__ rs, int* __restrict__ cur,
                               int* __restrict__ csrc, int E) {
    int i = blockIdx.x * blockDim.x + threadIdx.x;
    if (i >= E) return;
    int d = dst[i];
    int p = rs[d] + atomicAdd(&cur[d], 1);
    csrc[p] = src[i];
}

// ============================ merged prep: W fragments + wl/wr + zeroing ============================
__global__ void prep_all(const float* __restrict__ W0, const float* __restrict__ W1,
                         const float* __restrict__ W2, const float* __restrict__ al2,
                         const float* __restrict__ ar2, bf16x8* __restrict__ WFH,
                         bf16x8* __restrict__ WFL, float* __restrict__ wl,
                         float* __restrict__ wr, int* __restrict__ zerop, int nzero) {
    if (blockIdx.x < 48) {
        const int wid = blockIdx.x * 4 + (threadIdx.x >> 6);  // 0..191
        const int l = threadIdx.x & 63;
        const int lr = l & 15, lg = l >> 4;
        int t = wid;
        const float* srcp;
        int stride, coff;
        if (t < 32) { srcp = W0; stride = 128; coff = 0; }
        else if (t < 64) { srcp = W1; stride = 128; coff = 0; t -= 32; }
        else { t -= 64; srcp = W2; stride = 512; coff = (t >> 5) * 128; t &= 31; }
        const int kt = t >> 3, ct = t & 7;
        bf16x8 h8, l8;
#pragma unroll
        for (int j = 0; j < 8; ++j) {
            float w = srcp[(size_t)(kt * 32 + lg * 8 + j) * stride + coff + ct * 16 + lr];
            unsigned short hb = f2bf(w);
            h8[j] = (short)hb;
            l8[j] = (short)f2bf(w - bf2f(hb));
        }
        WFH[(size_t)wid * 64 + l] = h8;
        WFL[(size_t)wid * 64 + l] = l8;
    } else if (blockIdx.x == 48) {
        int idx = threadIdx.x;
#pragma unroll
        for (int k = 0; k < 2; ++k, idx += 256) {
            int h = idx >> 7, i = idx & 127;
            float sl = 0.0f, sr = 0.0f;
            for (int c = 0; c < 128; ++c) {
                float w = W2[(size_t)i * 512 + h * 128 + c];
                sl = fmaf(w, al2[h * 128 + c], sl);
                sr = fmaf(w, ar2[h * 128 + c], sr);
            }
            wl[idx] = sl;
            wr[idx] = sr;
        }
    } else {
        int idx = (blockIdx.x - 49) * 256 + threadIdx.x;
        if (idx < nzero) zerop[idx] = 0;
    }
}

// ============================ MFMA GEMM 128->128, bf16 f out, fused el/er ============================
// SPLIT_A=1: fp32 A input, split hi/lo (3 MFMA). SPLIT_A=0: bf16 A input (2 MFMA).
template <int SPLIT_A>
__global__ __launch_bounds__(256) void mfma_gemm128(const float* __restrict__ xf,
                                                    const unsigned short* __restrict__ xbf,
                                                    const bf16x8* __restrict__ BH,
                                                    const bf16x8* __restrict__ BL,
                                                    unsigned short* __restrict__ fbf,
                                                    const float* __restrict__ al,
                                                    const float* __restrict__ ar,
                                                    float* __restrict__ el,
                                                    float* __restrict__ er, int n) {
    const int tid = threadIdx.x;
    const int w = tid >> 6, l = tid & 63;
    const int lr = l & 15, lg = l >> 4;
    const int rowbase = blockIdx.x * 64 + w * 16;
    const int arow = rowbase + lr;

    f32x4 acc[8];
#pragma unroll
    for (int ct = 0; ct < 8; ++ct) acc[ct] = (f32x4){0.f, 0.f, 0.f, 0.f};

    for (int kt = 0; kt < 4; ++kt) {
        bf16x8 ah, alo;
        if (SPLIT_A) {
            float a[8];
            if (arow < n) {
                float4 p0 = *reinterpret_cast<const float4*>(&xf[(size_t)arow * 128 + kt * 32 + lg * 8]);
                float4 p1 = *reinterpret_cast<const float4*>(&xf[(size_t)arow * 128 + kt * 32 + lg * 8 + 4]);
                a[0] = p0.x; a[1] = p0.y; a[2] = p0.z; a[3] = p0.w;
                a[4] = p1.x; a[5] = p1.y; a[6] = p1.z; a[7] = p1.w;
            } else {
#pragma unroll
                for (int j = 0; j < 8; ++j) a[j] = 0.f;
            }
#pragma unroll
            for (int j = 0; j < 8; ++j) {
                unsigned short hb = f2bf(a[j]);
                ah[j] = (short)hb;
                alo[j] = (short)f2bf(a[j] - bf2f(hb));
            }
        } else {
            ah = (bf16x8){0, 0, 0, 0, 0, 0, 0, 0};
            if (arow < n)
                ah = *reinterpret_cast<const bf16x8*>(&xbf[(size_t)arow * 128 + kt * 32 + lg * 8]);
        }
        const bf16x8* bh = &BH[(size_t)(kt * 8) * 64 + l];
        const bf16x8* bl = &BL[(size_t)(kt * 8) * 64 + l];
#pragma unroll
        for (int ct = 0; ct < 8; ++ct) {
            bf16x8 b1 = bh[ct * 64];
            bf16x8 b2 = bl[ct * 64];
            acc[ct] = __builtin_amdgcn_mfma_f32_16x16x32_bf16(ah, b1, acc[ct], 0, 0, 0);
            if (SPLIT_A)
                acc[ct] = __builtin_amdgcn_mfma_f32_16x16x32_bf16(alo, b1, acc[ct], 0, 0, 0);
            acc[ct] = __builtin_amdgcn_mfma_f32_16x16x32_bf16(ah, b2, acc[ct], 0, 0, 0);
        }
    }
    // store f as bf16: D[row = lg*4+reg][col = ct*16+lr]
#pragma unroll
    for (int reg = 0; reg < 4; ++reg) {
        int orow = rowbase + lg * 4 + reg;
        if (orow < n) {
#pragma unroll
            for (int ct = 0; ct < 8; ++ct)
                fbf[(size_t)orow * 128 + ct * 16 + lr] = f2bf(acc[ct][reg]);
        }
    }
    float pel[4][4], per_[4][4];
#pragma unroll
    for (int h = 0; h < 4; ++h) {
        float a0 = al[h * 32 + lr], a1 = al[h * 32 + 16 + lr];
        float r0 = ar[h * 32 + lr], r1 = ar[h * 32 + 16 + lr];
#pragma unroll
        for (int reg = 0; reg < 4; ++reg) {
            pel[reg][h] = acc[2 * h][reg] * a0 + acc[2 * h + 1][reg] * a1;
            per_[reg][h] = acc[2 * h][reg] * r0 + acc[2 * h + 1][reg] * r1;
        }
    }
#pragma unroll
    for (int off = 1; off < 16; off <<= 1) {
#pragma unroll
        for (int reg = 0; reg < 4; ++reg)
#pragma unroll
            for (int h = 0; h < 4; ++h) {
                pel[reg][h] += __shfl_xor(pel[reg][h], off);
                per_[reg][h] += __shfl_xor(per_[reg][h], off);
            }
    }
    if (lr == 0) {
#pragma unroll
        for (int reg = 0; reg < 4; ++reg) {
            int orow = rowbase + lg * 4 + reg;
            if (orow < n) {
#pragma unroll
                for (int h = 0; h < 4; ++h) {
                    el[orow * HH + h] = pel[reg][h];
                    er[orow * HH + h] = per_[reg][h];
                }
            }
        }
    }
}

// ============================ MFMA block-diag GEMM + relu + pool + fused FC head ============================
__global__ __launch_bounds__(256) void mfma_bd_pool(const unsigned short* __restrict__ aggbf,
                                                    const bf16x8* __restrict__ WFH,
                                                    const bf16x8* __restrict__ WFL,
                                                    unsigned* __restrict__ pooled,
                                                    int* __restrict__ ticket,
                                                    const float* __restrict__ fcw,
                                                    const float* __restrict__ fcb,
                                                    float* __restrict__ outp, int n) {
    __shared__ float smax[4][128];
    __shared__ int isLast;
    const int tid = threadIdx.x;
    const int w = tid >> 6, l = tid & 63;
    const int lr = l & 15, lg = l >> 4;
    const int y = blockIdx.y;
    const int rowbase = blockIdx.x * 64 + w * 16;
    const int arow = rowbase + lr;
    const bf16x8* BH = WFH + (size_t)(64 + y * 32) * 64;
    const bf16x8* BL = WFL + (size_t)(64 + y * 32) * 64;

    f32x4 acc[8];
#pragma unroll
    for (int ct = 0; ct < 8; ++ct) acc[ct] = (f32x4){0.f, 0.f, 0.f, 0.f};

    for (int kt = 0; kt < 4; ++kt) {
        bf16x8 av = {0, 0, 0, 0, 0, 0, 0, 0};
        if (arow < n)
            av = *reinterpret_cast<const bf16x8*>(&aggbf[(size_t)arow * 512 + y * 128 + kt * 32 + lg * 8]);
        const bf16x8* bh = &BH[(size_t)(kt * 8) * 64 + l];
        const bf16x8* bl = &BL[(size_t)(kt * 8) * 64 + l];
#pragma unroll
        for (int ct = 0; ct < 8; ++ct) {
            acc[ct] = __builtin_amdgcn_mfma_f32_16x16x32_bf16(av, bh[ct * 64], acc[ct], 0, 0, 0);
            acc[ct] = __builtin_amdgcn_mfma_f32_16x16x32_bf16(av, bl[ct * 64], acc[ct], 0, 0, 0);
        }
    }
    float cm[8];
#pragma unroll
    for (int ct = 0; ct < 8; ++ct) {
        float v = fmaxf(fmaxf(acc[ct][0], acc[ct][1]), fmaxf(acc[ct][2], acc[ct][3]));
        cm[ct] = fmaxf(v, 0.f);
    }
#pragma unroll
    for (int ct = 0; ct < 8; ++ct) {
        cm[ct] = fmaxf(cm[ct], __shfl_xor(cm[ct], 16));
        cm[ct] = fmaxf(cm[ct], __shfl_xor(cm[ct], 32));
    }
    if (l < 16) {
#pragma unroll
        for (int ct = 0; ct < 8; ++ct) smax[w][ct * 16 + lr] = cm[ct];
    }
    __syncthreads();
    if (tid < 128) {
        float mx = fmaxf(fmaxf(smax[0][tid], smax[1][tid]), fmaxf(smax[2][tid], smax[3][tid]));
        atomicMax(&pooled[y * 128 + tid], __float_as_uint(mx));  // nonneg: uint order == float order
    }
    // fused head: last block to finish computes FC + softmax
    __syncthreads();
    if (tid == 0) {
        __threadfence();
        int done = atomicAdd(ticket, 1);
        isLast = (done == (int)(gridDim.x * gridDim.y) - 1);
    }
    __syncthreads();
    if (isLast) {
        __shared__ float logits[8];
        if (tid < 8) {
            float accl = fcb[tid];
            for (int i = 0; i < 512; ++i) {
                float pv = __uint_as_float(((volatile unsigned*)pooled)[i]);
                accl = fmaf(pv, fcw[i * 8 + tid], accl);
            }
            logits[tid] = accl;
        }
        __syncthreads();
        if (tid == 0) {
            float mx = -1e30f;
            for (int j = 0; j < 8; ++j) mx = fmaxf(mx, logits[j]);
            float ex[8], s = 0.0f;
            for (int j = 0; j < 8; ++j) { ex[j] = expf(logits[j] - mx); s += ex[j]; }
            for (int j = 0; j < 8; ++j) outp[j] = ex[j] / s;
        }
    }
}

// ============================ shuffle-free softmax-gather (K=128, bf16 f, bf16 out) ============================
template <int MODE>
__global__ __launch_bounds__(256) void aggr_wave128(const int* __restrict__ rs,
                                                    const int* __restrict__ csrc,
                                                    const float* __restrict__ el,
                                                    const float* __restrict__ er,
                                                    const unsigned short* __restrict__ fbf,
                                                    unsigned short* __restrict__ outbf,
                                                    const float* __restrict__ wl,
                                                    const float* __restrict__ wr,
                                                    float* __restrict__ el2,
                                                    float* __restrict__ er2, int n) {
    int d = blockIdx.x * 4 + (threadIdx.x >> 6);
    if (d >= n) return;
    d = __builtin_amdgcn_readfirstlane(d);  // wave-uniform -> scalar regs
    const int lane = threadIdx.x & 63;
    const int hg = lane >> 4;
    const int cb2 = lane * 2;
    const int e0 = __builtin_amdgcn_readfirstlane(rs[d]);
    const int e1 = __builtin_amdgcn_readfirstlane(rs[d + 1]);
    const float erd = er[d * HH + hg];

    float z = 0.f, a0 = 0.f, a1 = 0.f;
#pragma unroll 8
    for (int e = e0; e < e1; ++e) {
        int s = csrc[e];                       // scalar load (uniform addr)
        float v = el[s * HH + hg] + erd;       // one-line broadcast
        float wv = __expf(lrelu(v));
        z += wv;
        unsigned xu = *reinterpret_cast<const unsigned*>(&fbf[(size_t)s * 128 + cb2]);
        a0 = fmaf(wv, bf2f_lo(xu), a0);
        a1 = fmaf(wv, bf2f_hi(xu), a1);
    }
    const float rz = (z > 0.f) ? 1.0f / z : 0.f;
    a0 = fmaxf(a0 * rz, 0.f);  // relu'd output
    a1 = fmaxf(a1 * rz, 0.f);
    ushort2 sv;
    sv.x = f2bf(a0); sv.y = f2bf(a1);
    *reinterpret_cast<ushort2*>(&outbf[(size_t)d * 128 + cb2]) = sv;
    if (MODE == 1) {
        float pl[4], pr[4];
#pragma unroll
        for (int h = 0; h < 4; ++h) {
            float2 wlv = *reinterpret_cast<const float2*>(&wl[h * 128 + cb2]);
            float2 wrv = *reinterpret_cast<const float2*>(&wr[h * 128 + cb2]);
            pl[h] = a0 * wlv.x + a1 * wlv.y;
            pr[h] = a0 * wrv.x + a1 * wrv.y;
        }
#pragma unroll
        for (int off = 1; off < 64; off <<= 1) {
#pragma unroll
            for (int h = 0; h < 4; ++h) {
                pl[h] += __shfl_xor(pl[h], off);
                pr[h] += __shfl_xor(pr[h], off);
            }
        }
        if (lane == 0) {
#pragma unroll
            for (int h = 0; h < 4; ++h) {
                el2[d * HH + h] = pl[h];
                er2[d * HH + h] = pr[h];
            }
        }
    }
}

// ============================ layer 2: shuffle-free aggregate (4 head slices) ============================
__global__ __launch_bounds__(256) void aggr_x(const int* __restrict__ rs,
                                              const int* __restrict__ csrc,
                                              const float* __restrict__ el,
                                              const float* __restrict__ er,
                                              const unsigned short* __restrict__ xbf,
                                              unsigned short* __restrict__ aggbf, int n) {
    int d = blockIdx.x * 4 + (threadIdx.x >> 6);
    if (d >= n) return;
    d = __builtin_amdgcn_readfirstlane(d);
    const int lane = threadIdx.x & 63;
    const int hg = lane >> 4, j16 = lane & 15;
    const int e0 = __builtin_amdgcn_readfirstlane(rs[d]);
    const int e1 = __builtin_amdgcn_readfirstlane(rs[d + 1]);
    const float erd = er[d * HH + hg];

    float z = 0.f;
    float acc[8];
#pragma unroll
    for (int j = 0; j < 8; ++j) acc[j] = 0.f;
#pragma unroll 4
    for (int e = e0; e < e1; ++e) {
        int s = csrc[e];
        float v = el[s * HH + hg] + erd;
        float wv = __expf(lrelu(v));
        z += wv;
        uint4 xu = *reinterpret_cast<const uint4*>(&xbf[(size_t)s * 128 + j16 * 8]);
        acc[0] = fmaf(wv, bf2f_lo(xu.x), acc[0]);
        acc[1] = fmaf(wv, bf2f_hi(xu.x), acc[1]);
        acc[2] = fmaf(wv, bf2f_lo(xu.y), acc[2]);
        acc[3] = fmaf(wv, bf2f_hi(xu.y), acc[3]);
        acc[4] = fmaf(wv, bf2f_lo(xu.z), acc[4]);
        acc[5] = fmaf(wv, bf2f_hi(xu.z), acc[5]);
        acc[6] = fmaf(wv, bf2f_lo(xu.w), acc[6]);
        acc[7] = fmaf(wv, bf2f_hi(xu.w), acc[7]);
    }
    const float rz = (z > 0.f) ? 1.0f / z : 0.f;
    ushort4 s0, s1;
    s0.x = f2bf(acc[0] * rz); s0.y = f2bf(acc[1] * rz);
    s0.z = f2bf(acc[2] * rz); s0.w = f2bf(acc[3] * rz);
    s1.x = f2bf(acc[4] * rz); s1.y = f2bf(acc[5] * rz);
    s1.z = f2bf(acc[6] * rz); s1.w = f2bf(acc[7] * rz);
    unsigned short* op = &aggbf[(size_t)d * 512 + hg * 128 + j16 * 8];
    *reinterpret_cast<ushort4*>(op) = s0;
    *reinterpret_cast<ushort4*>(op + 4) = s1;
}

extern "C" void kernel_launch(void* const* d_in, const int* in_sizes, int n_in,
                              void* d_out, int out_size, void* d_ws, size_t ws_size,
                              hipStream_t stream) {
    const float* x0  = (const float*)d_in[0];
    const int*   src = (const int*)d_in[1];
    const int*   dst = (const int*)d_in[2];
    const float* W0  = (const float*)d_in[3];
    const float* al0 = (const float*)d_in[4];
    const float* ar0 = (const float*)d_in[5];
    const float* W1  = (const float*)d_in[6];
    const float* al1 = (const float*)d_in[7];
    const float* ar1 = (const float*)d_in[8];
    const float* W2  = (const float*)d_in[9];
    const float* al2 = (const float*)d_in[10];
    const float* ar2 = (const float*)d_in[11];
    const float* fcw = (const float*)d_in[12];
    const float* fcb = (const float*)d_in[13];
    float* outp = (float*)d_out;

    const int N = in_sizes[0] / 128;
    const int E = in_sizes[1];

    // -------- workspace layout (float units) --------
    float* el   = (float*)d_ws;                       // N*4
    float* er   = el + (size_t)N * HH;                // N*4
    float* el2  = er + (size_t)N * HH;                // N*4
    float* er2  = el2 + (size_t)N * HH;               // N*4
    float* wl   = er2 + (size_t)N * HH;               // 512
    float* wr   = wl + 512;                           // 512
    // contiguous zeroed region: deg(N), cur(N), pooled(512), ticket(1)
    int* deg  = (int*)(wr + 512);                     // N
    int* cur  = deg + N;                              // N
    float* pooled = (float*)(cur + N);                // 512
    int* ticket = (int*)(pooled + 512);               // 1
    int* rs   = ticket + 1;                           // N+1
    int* bsum = rs + (N + 1);                         // 64
    int* csrc = bsum + 64;                            // E
    unsigned short* Fbf   = (unsigned short*)(csrc + E);        // N*128 bf16
    unsigned short* B0bf  = Fbf + (size_t)N * 128;              // N*128 bf16
    unsigned short* B1bf  = B0bf + (size_t)N * 128;             // N*128 bf16
    unsigned short* AGGbf = B1bf + (size_t)N * 128;             // N*512 bf16
    uintptr_t wfaddr = ((uintptr_t)(AGGbf + (size_t)N * 512) + 15) & ~(uintptr_t)15;
    bf16x8* WFH = (bf16x8*)wfaddr;                    // 192*64 frags * 16 B
    bf16x8* WFL = WFH + (size_t)192 * 64;

    // -------- setup: merged prep(+zero) + CSR (parallel scan, merged top) --------
    const int nzero = 2 * N + 513;                    // deg + cur + pooled + ticket
    const int zb = (nzero + 255) / 256;
    prep_all<<<49 + zb, 256, 0, stream>>>(W0, W1, W2, al2, ar2, WFH, WFL, wl, wr, deg, nzero);
    hist_kernel<<<(E + 255) / 256, 256, 0, stream>>>(dst, deg, E);
    const int nb = (N + 1023) / 1024;
    scan_block<<<nb, 1024, 0, stream>>>(deg, rs, bsum, N);
    scan_add<<<(N + 255) / 256, 256, 0, stream>>>(rs, bsum, N);
    scatter_kernel<<<(E + 255) / 256, 256, 0, stream>>>(src, dst, rs, cur, csrc, E);

    const int rowTiles = (N + 63) / 64;
    const int nodeBlocks = (N + 3) / 4;

    // -------- layer 0 (fp32 A, split) --------
    mfma_gemm128<1><<<rowTiles, 256, 0, stream>>>(x0, nullptr, WFH, WFL, Fbf, al0, ar0, el, er, N);
    aggr_wave128<0><<<nodeBlocks, 256, 0, stream>>>(rs, csrc, el, er, Fbf, B0bf,
                                                    nullptr, nullptr, nullptr, nullptr, N);
    // -------- layer 1 (bf16 A, no split; aggr fuses el2/er2) --------
    mfma_gemm128<0><<<rowTiles, 256, 0, stream>>>(nullptr, B0bf, WFH + (size_t)32 * 64,
                                                  WFL + (size_t)32 * 64, Fbf, al1, ar1, el, er, N);
    aggr_wave128<1><<<nodeBlocks, 256, 0, stream>>>(rs, csrc, el, er, Fbf, B1bf,
                                                    wl, wr, el2, er2, N);
    // -------- layer 2 (bf16 gather -> bf16 AGG -> MFMA + pool + fused head) --------
    aggr_x<<<nodeBlocks, 256, 0, stream>>>(rs, csrc, el2, er2, B1bf, AGGbf, N);
    mfma_bd_pool<<<dim3(rowTiles, 4), 256, 0, stream>>>(AGGbf, WFH, WFL, (unsigned*)pooled,
                                                        ticket, fcw, fcb, outp, N);
}

// Round 16
// 232.877 us; speedup vs baseline: 1.3226x; 1.3226x over previous
//
#include <hip/hip_runtime.h>

#define HH 4  // heads

typedef __attribute__((ext_vector_type(8))) short bf16x8;
typedef __attribute__((ext_vector_type(4))) float f32x4;

__device__ __forceinline__ float lrelu(float v) { return (v >= 0.0f) ? v : 0.2f * v; }

__device__ __forceinline__ unsigned short f2bf(float x) {
    union { float f; unsigned u; } v; v.f = x;
    unsigned r = (v.u + 0x7FFFu + ((v.u >> 16) & 1u)) >> 16;
    return (unsigned short)r;
}
__device__ __forceinline__ float bf2f(unsigned short b) {
    union { unsigned u; float f; } v; v.u = ((unsigned)b) << 16;
    return v.f;
}
__device__ __forceinline__ float bf2f_lo(unsigned u) {
    union { unsigned x; float f; } v; v.x = u << 16;
    return v.f;
}
__device__ __forceinline__ float bf2f_hi(unsigned u) {
    union { unsigned x; float f; } v; v.x = u & 0xffff0000u;
    return v.f;
}

// ============================ CSR build ============================
__global__ void hist_kernel(const int* __restrict__ dst, int* __restrict__ deg, int E) {
    int i = blockIdx.x * blockDim.x + threadIdx.x;
    if (i < E) atomicAdd(&deg[dst[i]], 1);
}

__global__ void scan_block(const int* __restrict__ deg, int* __restrict__ rs,
                           int* __restrict__ bsum, int n) {
    __shared__ int buf[1024];
    int i = blockIdx.x * 1024 + threadIdx.x;
    int v = (i < n) ? deg[i] : 0;
    buf[threadIdx.x] = v;
    __syncthreads();
    for (int off = 1; off < 1024; off <<= 1) {
        int t = (threadIdx.x >= off) ? buf[threadIdx.x - off] : 0;
        __syncthreads();
        buf[threadIdx.x] += t;
        __syncthreads();
    }
    if (i < n) rs[i + 1] = buf[threadIdx.x];
    if (threadIdx.x == 1023) bsum[blockIdx.x] = buf[1023];
}

// merged top-level scan: each thread serially prefixes bsum (<=30 entries, L2-hot)
__global__ void scan_add(int* __restrict__ rs, const int* __restrict__ bsum, int n) {
    int i = blockIdx.x * blockDim.x + threadIdx.x;
    if (i == 0) rs[0] = 0;
    if (i < n) {
        int blk = i >> 10;
        int pre = 0;
        for (int b = 0; b < blk; ++b) pre += bsum[b];
        rs[i + 1] += pre;
    }
}

__global__ void scatter_kernel(const int* __restrict__ src, const int* __restrict__ dst,
                               const int* __restrict__ rs, int* __restrict__ cur,
                               int* __restrict__ csrc, int E) {
    int i = blockIdx.x * blockDim.x + threadIdx.x;
    if (i >= E) return;
    int d = dst[i];
    int p = rs[d] + atomicAdd(&cur[d], 1);
    csrc[p] = src[i];
}

// ============================ merged prep: W fragments + wl/wr + zeroing ============================
__global__ void prep_all(const float* __restrict__ W0, const float* __restrict__ W1,
                         const float* __restrict__ W2, const float* __restrict__ al2,
                         const float* __restrict__ ar2, bf16x8* __restrict__ WFH,
                         bf16x8* __restrict__ WFL, float* __restrict__ wl,
                         float* __restrict__ wr, int* __restrict__ zerop, int nzero) {
    if (blockIdx.x < 48) {
        const int wid = blockIdx.x * 4 + (threadIdx.x >> 6);  // 0..191
        const int l = threadIdx.x & 63;
        const int lr = l & 15, lg = l >> 4;
        int t = wid;
        const float* srcp;
        int stride, coff;
        if (t < 32) { srcp = W0; stride = 128; coff = 0; }
        else if (t < 64) { srcp = W1; stride = 128; coff = 0; t -= 32; }
        else { t -= 64; srcp = W2; stride = 512; coff = (t >> 5) * 128; t &= 31; }
        const int kt = t >> 3, ct = t & 7;
        bf16x8 h8, l8;
#pragma unroll
        for (int j = 0; j < 8; ++j) {
            float w = srcp[(size_t)(kt * 32 + lg * 8 + j) * stride + coff + ct * 16 + lr];
            unsigned short hb = f2bf(w);
            h8[j] = (short)hb;
            l8[j] = (short)f2bf(w - bf2f(hb));
        }
        WFH[(size_t)wid * 64 + l] = h8;
        WFL[(size_t)wid * 64 + l] = l8;
    } else if (blockIdx.x == 48) {
        int idx = threadIdx.x;
#pragma unroll
        for (int k = 0; k < 2; ++k, idx += 256) {
            int h = idx >> 7, i = idx & 127;
            float sl = 0.0f, sr = 0.0f;
            for (int c = 0; c < 128; ++c) {
                float w = W2[(size_t)i * 512 + h * 128 + c];
                sl = fmaf(w, al2[h * 128 + c], sl);
                sr = fmaf(w, ar2[h * 128 + c], sr);
            }
            wl[idx] = sl;
            wr[idx] = sr;
        }
    } else {
        int idx = (blockIdx.x - 49) * 256 + threadIdx.x;
        if (idx < nzero) zerop[idx] = 0;
    }
}

// ============================ MFMA GEMM 128->128, bf16 f out, fused el/er ============================
// SPLIT_A=1: fp32 A input, split hi/lo (3 MFMA). SPLIT_A=0: bf16 A input (2 MFMA).
template <int SPLIT_A>
__global__ __launch_bounds__(256) void mfma_gemm128(const float* __restrict__ xf,
                                                    const unsigned short* __restrict__ xbf,
                                                    const bf16x8* __restrict__ BH,
                                                    const bf16x8* __restrict__ BL,
                                                    unsigned short* __restrict__ fbf,
                                                    const float* __restrict__ al,
                                                    const float* __restrict__ ar,
                                                    float* __restrict__ el,
                                                    float* __restrict__ er, int n) {
    const int tid = threadIdx.x;
    const int w = tid >> 6, l = tid & 63;
    const int lr = l & 15, lg = l >> 4;
    const int rowbase = blockIdx.x * 64 + w * 16;
    const int arow = rowbase + lr;

    f32x4 acc[8];
#pragma unroll
    for (int ct = 0; ct < 8; ++ct) acc[ct] = (f32x4){0.f, 0.f, 0.f, 0.f};

    for (int kt = 0; kt < 4; ++kt) {
        bf16x8 ah, alo;
        if (SPLIT_A) {
            float a[8];
            if (arow < n) {
                float4 p0 = *reinterpret_cast<const float4*>(&xf[(size_t)arow * 128 + kt * 32 + lg * 8]);
                float4 p1 = *reinterpret_cast<const float4*>(&xf[(size_t)arow * 128 + kt * 32 + lg * 8 + 4]);
                a[0] = p0.x; a[1] = p0.y; a[2] = p0.z; a[3] = p0.w;
                a[4] = p1.x; a[5] = p1.y; a[6] = p1.z; a[7] = p1.w;
            } else {
#pragma unroll
                for (int j = 0; j < 8; ++j) a[j] = 0.f;
            }
#pragma unroll
            for (int j = 0; j < 8; ++j) {
                unsigned short hb = f2bf(a[j]);
                ah[j] = (short)hb;
                alo[j] = (short)f2bf(a[j] - bf2f(hb));
            }
        } else {
            ah = (bf16x8){0, 0, 0, 0, 0, 0, 0, 0};
            if (arow < n)
                ah = *reinterpret_cast<const bf16x8*>(&xbf[(size_t)arow * 128 + kt * 32 + lg * 8]);
        }
        const bf16x8* bh = &BH[(size_t)(kt * 8) * 64 + l];
        const bf16x8* bl = &BL[(size_t)(kt * 8) * 64 + l];
#pragma unroll
        for (int ct = 0; ct < 8; ++ct) {
            bf16x8 b1 = bh[ct * 64];
            bf16x8 b2 = bl[ct * 64];
            acc[ct] = __builtin_amdgcn_mfma_f32_16x16x32_bf16(ah, b1, acc[ct], 0, 0, 0);
            if (SPLIT_A)
                acc[ct] = __builtin_amdgcn_mfma_f32_16x16x32_bf16(alo, b1, acc[ct], 0, 0, 0);
            acc[ct] = __builtin_amdgcn_mfma_f32_16x16x32_bf16(ah, b2, acc[ct], 0, 0, 0);
        }
    }
    // store f as bf16: D[row = lg*4+reg][col = ct*16+lr]
#pragma unroll
    for (int reg = 0; reg < 4; ++reg) {
        int orow = rowbase + lg * 4 + reg;
        if (orow < n) {
#pragma unroll
            for (int ct = 0; ct < 8; ++ct)
                fbf[(size_t)orow * 128 + ct * 16 + lr] = f2bf(acc[ct][reg]);
        }
    }
    float pel[4][4], per_[4][4];
#pragma unroll
    for (int h = 0; h < 4; ++h) {
        float a0 = al[h * 32 + lr], a1 = al[h * 32 + 16 + lr];
        float r0 = ar[h * 32 + lr], r1 = ar[h * 32 + 16 + lr];
#pragma unroll
        for (int reg = 0; reg < 4; ++reg) {
            pel[reg][h] = acc[2 * h][reg] * a0 + acc[2 * h + 1][reg] * a1;
            per_[reg][h] = acc[2 * h][reg] * r0 + acc[2 * h + 1][reg] * r1;
        }
    }
#pragma unroll
    for (int off = 1; off < 16; off <<= 1) {
#pragma unroll
        for (int reg = 0; reg < 4; ++reg)
#pragma unroll
            for (int h = 0; h < 4; ++h) {
                pel[reg][h] += __shfl_xor(pel[reg][h], off);
                per_[reg][h] += __shfl_xor(per_[reg][h], off);
            }
    }
    if (lr == 0) {
#pragma unroll
        for (int reg = 0; reg < 4; ++reg) {
            int orow = rowbase + lg * 4 + reg;
            if (orow < n) {
#pragma unroll
                for (int h = 0; h < 4; ++h) {
                    el[orow * HH + h] = pel[reg][h];
                    er[orow * HH + h] = per_[reg][h];
                }
            }
        }
    }
}

// ============================ MFMA block-diag GEMM (bf16 A) + relu + global max pool ============================
__global__ __launch_bounds__(256) void mfma_bd_pool(const unsigned short* __restrict__ aggbf,
                                                    const bf16x8* __restrict__ WFH,
                                                    const bf16x8* __restrict__ WFL,
                                                    unsigned* __restrict__ pooled, int n) {
    __shared__ float smax[4][128];
    const int tid = threadIdx.x;
    const int w = tid >> 6, l = tid & 63;
    const int lr = l & 15, lg = l >> 4;
    const int y = blockIdx.y;
    const int rowbase = blockIdx.x * 64 + w * 16;
    const int arow = rowbase + lr;
    const bf16x8* BH = WFH + (size_t)(64 + y * 32) * 64;
    const bf16x8* BL = WFL + (size_t)(64 + y * 32) * 64;

    f32x4 acc[8];
#pragma unroll
    for (int ct = 0; ct < 8; ++ct) acc[ct] = (f32x4){0.f, 0.f, 0.f, 0.f};

    for (int kt = 0; kt < 4; ++kt) {
        bf16x8 av = {0, 0, 0, 0, 0, 0, 0, 0};
        if (arow < n)
            av = *reinterpret_cast<const bf16x8*>(&aggbf[(size_t)arow * 512 + y * 128 + kt * 32 + lg * 8]);
        const bf16x8* bh = &BH[(size_t)(kt * 8) * 64 + l];
        const bf16x8* bl = &BL[(size_t)(kt * 8) * 64 + l];
#pragma unroll
        for (int ct = 0; ct < 8; ++ct) {
            acc[ct] = __builtin_amdgcn_mfma_f32_16x16x32_bf16(av, bh[ct * 64], acc[ct], 0, 0, 0);
            acc[ct] = __builtin_amdgcn_mfma_f32_16x16x32_bf16(av, bl[ct * 64], acc[ct], 0, 0, 0);
        }
    }
    float cm[8];
#pragma unroll
    for (int ct = 0; ct < 8; ++ct) {
        float v = fmaxf(fmaxf(acc[ct][0], acc[ct][1]), fmaxf(acc[ct][2], acc[ct][3]));
        cm[ct] = fmaxf(v, 0.f);
    }
#pragma unroll
    for (int ct = 0; ct < 8; ++ct) {
        cm[ct] = fmaxf(cm[ct], __shfl_xor(cm[ct], 16));
        cm[ct] = fmaxf(cm[ct], __shfl_xor(cm[ct], 32));
    }
    if (l < 16) {
#pragma unroll
        for (int ct = 0; ct < 8; ++ct) smax[w][ct * 16 + lr] = cm[ct];
    }
    __syncthreads();
    if (tid < 128) {
        float mx = fmaxf(fmaxf(smax[0][tid], smax[1][tid]), fmaxf(smax[2][tid], smax[3][tid]));
        atomicMax(&pooled[y * 128 + tid], __float_as_uint(mx));  // nonneg: uint order == float order
    }
}

// ============================ shuffle-free softmax-gather (K=128, bf16 f, bf16 out) ============================
template <int MODE>
__global__ __launch_bounds__(256) void aggr_wave128(const int* __restrict__ rs,
                                                    const int* __restrict__ csrc,
                                                    const float* __restrict__ el,
                                                    const float* __restrict__ er,
                                                    const unsigned short* __restrict__ fbf,
                                                    unsigned short* __restrict__ outbf,
                                                    const float* __restrict__ wl,
                                                    const float* __restrict__ wr,
                                                    float* __restrict__ el2,
                                                    float* __restrict__ er2, int n) {
    int d = blockIdx.x * 4 + (threadIdx.x >> 6);
    if (d >= n) return;
    d = __builtin_amdgcn_readfirstlane(d);  // wave-uniform -> scalar regs
    const int lane = threadIdx.x & 63;
    const int hg = lane >> 4;
    const int cb2 = lane * 2;
    const int e0 = __builtin_amdgcn_readfirstlane(rs[d]);
    const int e1 = __builtin_amdgcn_readfirstlane(rs[d + 1]);
    const float erd = er[d * HH + hg];

    float z = 0.f, a0 = 0.f, a1 = 0.f;
#pragma unroll 8
    for (int e = e0; e < e1; ++e) {
        int s = csrc[e];                       // scalar load (uniform addr)
        float v = el[s * HH + hg] + erd;       // one-line broadcast
        float wv = __expf(lrelu(v));
        z += wv;
        unsigned xu = *reinterpret_cast<const unsigned*>(&fbf[(size_t)s * 128 + cb2]);
        a0 = fmaf(wv, bf2f_lo(xu), a0);
        a1 = fmaf(wv, bf2f_hi(xu), a1);
    }
    const float rz = (z > 0.f) ? 1.0f / z : 0.f;
    a0 = fmaxf(a0 * rz, 0.f);  // relu'd output
    a1 = fmaxf(a1 * rz, 0.f);
    ushort2 sv;
    sv.x = f2bf(a0); sv.y = f2bf(a1);
    *reinterpret_cast<ushort2*>(&outbf[(size_t)d * 128 + cb2]) = sv;
    if (MODE == 1) {
        float pl[4], pr[4];
#pragma unroll
        for (int h = 0; h < 4; ++h) {
            float2 wlv = *reinterpret_cast<const float2*>(&wl[h * 128 + cb2]);
            float2 wrv = *reinterpret_cast<const float2*>(&wr[h * 128 + cb2]);
            pl[h] = a0 * wlv.x + a1 * wlv.y;
            pr[h] = a0 * wrv.x + a1 * wrv.y;
        }
#pragma unroll
        for (int off = 1; off < 64; off <<= 1) {
#pragma unroll
            for (int h = 0; h < 4; ++h) {
                pl[h] += __shfl_xor(pl[h], off);
                pr[h] += __shfl_xor(pr[h], off);
            }
        }
        if (lane == 0) {
#pragma unroll
            for (int h = 0; h < 4; ++h) {
                el2[d * HH + h] = pl[h];
                er2[d * HH + h] = pr[h];
            }
        }
    }
}

// ============================ layer 2: shuffle-free aggregate (4 head slices) ============================
__global__ __launch_bounds__(256) void aggr_x(const int* __restrict__ rs,
                                              const int* __restrict__ csrc,
                                              const float* __restrict__ el,
                                              const float* __restrict__ er,
                                              const unsigned short* __restrict__ xbf,
                                              unsigned short* __restrict__ aggbf, int n) {
    int d = blockIdx.x * 4 + (threadIdx.x >> 6);
    if (d >= n) return;
    d = __builtin_amdgcn_readfirstlane(d);
    const int lane = threadIdx.x & 63;
    const int hg = lane >> 4, j16 = lane & 15;
    const int e0 = __builtin_amdgcn_readfirstlane(rs[d]);
    const int e1 = __builtin_amdgcn_readfirstlane(rs[d + 1]);
    const float erd = er[d * HH + hg];

    float z = 0.f;
    float acc[8];
#pragma unroll
    for (int j = 0; j < 8; ++j) acc[j] = 0.f;
#pragma unroll 4
    for (int e = e0; e < e1; ++e) {
        int s = csrc[e];
        float v = el[s * HH + hg] + erd;
        float wv = __expf(lrelu(v));
        z += wv;
        uint4 xu = *reinterpret_cast<const uint4*>(&xbf[(size_t)s * 128 + j16 * 8]);
        acc[0] = fmaf(wv, bf2f_lo(xu.x), acc[0]);
        acc[1] = fmaf(wv, bf2f_hi(xu.x), acc[1]);
        acc[2] = fmaf(wv, bf2f_lo(xu.y), acc[2]);
        acc[3] = fmaf(wv, bf2f_hi(xu.y), acc[3]);
        acc[4] = fmaf(wv, bf2f_lo(xu.z), acc[4]);
        acc[5] = fmaf(wv, bf2f_hi(xu.z), acc[5]);
        acc[6] = fmaf(wv, bf2f_lo(xu.w), acc[6]);
        acc[7] = fmaf(wv, bf2f_hi(xu.w), acc[7]);
    }
    const float rz = (z > 0.f) ? 1.0f / z : 0.f;
    ushort4 s0, s1;
    s0.x = f2bf(acc[0] * rz); s0.y = f2bf(acc[1] * rz);
    s0.z = f2bf(acc[2] * rz); s0.w = f2bf(acc[3] * rz);
    s1.x = f2bf(acc[4] * rz); s1.y = f2bf(acc[5] * rz);
    s1.z = f2bf(acc[6] * rz); s1.w = f2bf(acc[7] * rz);
    unsigned short* op = &aggbf[(size_t)d * 512 + hg * 128 + j16 * 8];
    *reinterpret_cast<ushort4*>(op) = s0;
    *reinterpret_cast<ushort4*>(op + 4) = s1;
}

// ============================ FC head + softmax ============================
__global__ void head_kernel(const float* __restrict__ pooled, const float* __restrict__ fcw,
                            const float* __restrict__ fcb, float* __restrict__ out) {
    __shared__ float logits[8];
    int t = threadIdx.x;
    if (t < 8) {
        float acc = fcb[t];
        for (int i = 0; i < 512; ++i) acc = fmaf(pooled[i], fcw[i * 8 + t], acc);
        logits[t] = acc;
    }
    __syncthreads();
    if (t == 0) {
        float mx = -1e30f;
        for (int j = 0; j < 8; ++j) mx = fmaxf(mx, logits[j]);
        float ex[8], s = 0.0f;
        for (int j = 0; j < 8; ++j) { ex[j] = expf(logits[j] - mx); s += ex[j]; }
        for (int j = 0; j < 8; ++j) out[j] = ex[j] / s;
    }
}

extern "C" void kernel_launch(void* const* d_in, const int* in_sizes, int n_in,
                              void* d_out, int out_size, void* d_ws, size_t ws_size,
                              hipStream_t stream) {
    const float* x0  = (const float*)d_in[0];
    const int*   src = (const int*)d_in[1];
    const int*   dst = (const int*)d_in[2];
    const float* W0  = (const float*)d_in[3];
    const float* al0 = (const float*)d_in[4];
    const float* ar0 = (const float*)d_in[5];
    const float* W1  = (const float*)d_in[6];
    const float* al1 = (const float*)d_in[7];
    const float* ar1 = (const float*)d_in[8];
    const float* W2  = (const float*)d_in[9];
    const float* al2 = (const float*)d_in[10];
    const float* ar2 = (const float*)d_in[11];
    const float* fcw = (const float*)d_in[12];
    const float* fcb = (const float*)d_in[13];
    float* outp = (float*)d_out;

    const int N = in_sizes[0] / 128;
    const int E = in_sizes[1];

    // -------- workspace layout (float units) --------
    float* el   = (float*)d_ws;                       // N*4
    float* er   = el + (size_t)N * HH;                // N*4
    float* el2  = er + (size_t)N * HH;                // N*4
    float* er2  = el2 + (size_t)N * HH;               // N*4
    float* wl   = er2 + (size_t)N * HH;               // 512
    float* wr   = wl + 512;                           // 512
    // contiguous zeroed region: deg(N), cur(N), pooled(512)
    int* deg  = (int*)(wr + 512);                     // N
    int* cur  = deg + N;                              // N
    float* pooled = (float*)(cur + N);                // 512
    int* rs   = (int*)(pooled + 512);                 // N+1
    int* bsum = rs + (N + 1);                         // 64
    int* csrc = bsum + 64;                            // E
    unsigned short* Fbf   = (unsigned short*)(csrc + E);        // N*128 bf16
    unsigned short* B0bf  = Fbf + (size_t)N * 128;              // N*128 bf16
    unsigned short* B1bf  = B0bf + (size_t)N * 128;             // N*128 bf16
    unsigned short* AGGbf = B1bf + (size_t)N * 128;             // N*512 bf16
    uintptr_t wfaddr = ((uintptr_t)(AGGbf + (size_t)N * 512) + 15) & ~(uintptr_t)15;
    bf16x8* WFH = (bf16x8*)wfaddr;                    // 192*64 frags * 16 B
    bf16x8* WFL = WFH + (size_t)192 * 64;

    // -------- setup: merged prep(+zero) + CSR (parallel scan, merged top) --------
    const int nzero = 2 * N + 512;                    // deg + cur + pooled
    const int zb = (nzero + 255) / 256;
    prep_all<<<49 + zb, 256, 0, stream>>>(W0, W1, W2, al2, ar2, WFH, WFL, wl, wr, deg, nzero);
    hist_kernel<<<(E + 255) / 256, 256, 0, stream>>>(dst, deg, E);
    const int nb = (N + 1023) / 1024;
    scan_block<<<nb, 1024, 0, stream>>>(deg, rs, bsum, N);
    scan_add<<<(N + 255) / 256, 256, 0, stream>>>(rs, bsum, N);
    scatter_kernel<<<(E + 255) / 256, 256, 0, stream>>>(src, dst, rs, cur, csrc, E);

    const int rowTiles = (N + 63) / 64;
    const int nodeBlocks = (N + 3) / 4;

    // -------- layer 0 (fp32 A, split) --------
    mfma_gemm128<1><<<rowTiles, 256, 0, stream>>>(x0, nullptr, WFH, WFL, Fbf, al0, ar0, el, er, N);
    aggr_wave128<0><<<nodeBlocks, 256, 0, stream>>>(rs, csrc, el, er, Fbf, B0bf,
                                                    nullptr, nullptr, nullptr, nullptr, N);
    // -------- layer 1 (bf16 A, no split; aggr fuses el2/er2) --------
    mfma_gemm128<0><<<rowTiles, 256, 0, stream>>>(nullptr, B0bf, WFH + (size_t)32 * 64,
                                                  WFL + (size_t)32 * 64, Fbf, al1, ar1, el, er, N);
    aggr_wave128<1><<<nodeBlocks, 256, 0, stream>>>(rs, csrc, el, er, Fbf, B1bf,
                                                    wl, wr, el2, er2, N);
    // -------- layer 2 (bf16 gather -> bf16 AGG -> MFMA + pool) --------
    aggr_x<<<nodeBlocks, 256, 0, stream>>>(rs, csrc, el2, er2, B1bf, AGGbf, N);
    mfma_bd_pool<<<dim3(rowTiles, 4), 256, 0, stream>>>(AGGbf, WFH, WFL, (unsigned*)pooled, N);

    head_kernel<<<1, 64, 0, stream>>>(pooled, fcw, fcb, outp);
}